// Round 1
// baseline (337.911 us; speedup 1.0000x reference)
//
#include <hip/hip_runtime.h>

using u16   = unsigned short;
using f32x4 = __attribute__((ext_vector_type(4))) float;
using s16x8 = __attribute__((ext_vector_type(8))) short;
using u32x2 = __attribute__((ext_vector_type(2))) unsigned int;
using u32x4 = __attribute__((ext_vector_type(4))) unsigned int;

#define LOG2E 1.44269504088896f

static __device__ __forceinline__ u16 f2bf(float f) {
  union { float f; unsigned u; } a; a.f = f;
  unsigned r = a.u + 0x7fffu + ((a.u >> 16) & 1u);
  return (u16)(r >> 16);
}
static __device__ __forceinline__ float bf2f(u16 h) {
  union { unsigned u; float f; } a; a.u = ((unsigned)h) << 16; return a.f;
}

// global(16B per lane, per-lane src addr) -> LDS (wave-uniform base + lane*16)
static __device__ __forceinline__ void gload16(const void* g, void* l) {
  __builtin_amdgcn_global_load_lds(
      (__attribute__((address_space(1))) unsigned int*)g,
      (__attribute__((address_space(3))) unsigned int*)l, 16, 0, 0);
}

// ---------------- LayerNorm + cast to bf16 (row = 1024) ----------------
__global__ __launch_bounds__(256) void ln_cast_k(
    const float* __restrict__ x, const float* __restrict__ gam,
    const float* __restrict__ bet, u16* __restrict__ out)
{
  const int row = blockIdx.x, t = threadIdx.x;
  const float4 v = ((const float4*)(x + (size_t)row * 1024))[t];
  float s  = v.x + v.y + v.z + v.w;
  float ss = v.x*v.x + v.y*v.y + v.z*v.z + v.w*v.w;
  #pragma unroll
  for (int m = 1; m < 64; m <<= 1) { s += __shfl_xor(s, m); ss += __shfl_xor(ss, m); }
  __shared__ float red[8];
  const int w = t >> 6;
  if ((t & 63) == 0) { red[w] = s; red[4 + w] = ss; }
  __syncthreads();
  s  = red[0] + red[1] + red[2] + red[3];
  ss = red[4] + red[5] + red[6] + red[7];
  const float mu   = s * (1.0f / 1024.0f);
  const float rstd = rsqrtf(ss * (1.0f / 1024.0f) - mu * mu + 1e-5f);
  const float4 gv = ((const float4*)gam)[t];
  const float4 bv = ((const float4*)bet)[t];
  ushort4 o;
  o.x = f2bf((v.x - mu) * rstd * gv.x + bv.x);
  o.y = f2bf((v.y - mu) * rstd * gv.y + bv.y);
  o.z = f2bf((v.z - mu) * rstd * gv.z + bv.z);
  o.w = f2bf((v.w - mu) * rstd * gv.w + bv.w);
  ((ushort4*)(out + (size_t)row * 1024))[t] = o;
}

// ---------------- f32 -> bf16 cast ----------------
__global__ __launch_bounds__(256) void cast_k(
    const float* __restrict__ in, u16* __restrict__ out, int n4)
{
  const int i = blockIdx.x * 256 + threadIdx.x;
  if (i >= n4) return;
  const float4 v = ((const float4*)in)[i];
  ushort4 o;
  o.x = f2bf(v.x); o.y = f2bf(v.y); o.z = f2bf(v.z); o.w = f2bf(v.w);
  ((ushort4*)out)[i] = o;
}

// ---------------- GEMM: C[M,N] = A[M,K] @ B[N,K]^T (bf16 in, f32 acc) ----------------
// 128x128 tile, 4 waves (2x2, each 64x64 = 4x4 frags of 16x16), BK=32.
template<int BIAS, int RES, int SILU, int OF32, int OBF>
__global__ __launch_bounds__(256, 2) void gemm_bt(
    const u16* __restrict__ A, const u16* __restrict__ B,
    u16* __restrict__ Cb, float* __restrict__ Cf,
    const float* __restrict__ bias, const float* __restrict__ resid,
    int M, int N, int K)
{
  __shared__ u16 As[128 * 32];
  __shared__ u16 Bs[128 * 32];
  const int tid = threadIdx.x;
  const int w = tid >> 6, l = tid & 63;
  const int g = l >> 4, q = l & 15;
  const int ntn = N >> 7;
  const int bm = blockIdx.x / ntn, bn = blockIdx.x - bm * ntn;
  const int wr = w >> 1, wc = w & 1;
  f32x4 acc[4][4] = {};

  const size_t abase = (size_t)(bm * 128) * K;
  const size_t bbase = (size_t)(bn * 128) * K;

  for (int k0 = 0; k0 < K; k0 += 32) {
    __syncthreads();
    #pragma unroll
    for (int r = 0; r < 2; ++r) {
      const int c = (r << 8) + (w << 6) + l;   // chunk 0..511 (16B each)
      const int row = c >> 2, part = c & 3;    // 128 rows x 4 parts (8 bf16)
      gload16(A + abase + (size_t)row * K + k0 + part * 8,
              &As[(size_t)((r << 8) + (w << 6)) * 8]);
      gload16(B + bbase + (size_t)row * K + k0 + part * 8,
              &Bs[(size_t)((r << 8) + (w << 6)) * 8]);
    }
    __syncthreads();
    s16x8 af[4], bfr[4];
    #pragma unroll
    for (int m = 0; m < 4; ++m)
      af[m] = *(const s16x8*)&As[(wr * 64 + m * 16 + q) * 32 + g * 8];
    #pragma unroll
    for (int n = 0; n < 4; ++n)
      bfr[n] = *(const s16x8*)&Bs[(wc * 64 + n * 16 + q) * 32 + g * 8];
    #pragma unroll
    for (int m = 0; m < 4; ++m)
      #pragma unroll
      for (int n = 0; n < 4; ++n)
        acc[m][n] = __builtin_amdgcn_mfma_f32_16x16x32_bf16(af[m], bfr[n], acc[m][n], 0, 0, 0);
  }

  #pragma unroll
  for (int m = 0; m < 4; ++m) {
    const int row0 = bm * 128 + wr * 64 + m * 16 + g * 4;
    #pragma unroll
    for (int n = 0; n < 4; ++n) {
      const int col = bn * 128 + wc * 64 + n * 16 + q;
      float bv = 0.0f;
      if (BIAS) bv = bias[col];
      #pragma unroll
      for (int r = 0; r < 4; ++r) {
        const size_t idx = (size_t)(row0 + r) * N + col;
        float v = acc[m][n][r] + bv;
        if (RES)  v += resid[idx];
        if (SILU) v = v / (1.0f + __expf(-v));
        if (OF32) Cf[idx] = v;
        if (OBF)  Cb[idx] = f2bf(v);
      }
    }
  }
}

// ---------------- Flash attention ----------------
// grid = bh*32 + qtile. 4 waves x 16 q-rows (Q-tile 64). KV-tile 64. HD=64.
// K staged with XOR-swizzle (pre-swizzled global src, linear LDS dest);
// V staged into 4x16-subtiled layout for ds_read_b64_tr_b16.
__global__ __launch_bounds__(256, 2) void attn_k(
    const u16* __restrict__ Q, const u16* __restrict__ KV, u16* __restrict__ O)
{
  __shared__ u16 Ks[64 * 64];
  __shared__ u16 Vs[64 * 64];
  __shared__ u16 Ps[4 * 16 * 64];
  const int tid = threadIdx.x;
  const int w = tid >> 6, l = tid & 63;
  const int g = l >> 4, q = l & 15;
  const int bh = blockIdx.x >> 5, qt = blockIdx.x & 31;
  const int b = bh >> 4, h = bh & 15;

  // Q fragments (16 rows x 64), pre-scaled by 1/8 (exact in bf16)
  const size_t qrow = (size_t)(b * 2048 + qt * 64 + w * 16 + q);
  s16x8 qf[2];
  #pragma unroll
  for (int s = 0; s < 2; ++s) {
    s16x8 t = *(const s16x8*)&Q[qrow * 1024 + h * 64 + s * 32 + g * 8];
    #pragma unroll
    for (int j = 0; j < 8; ++j)
      t[j] = (short)f2bf(bf2f((u16)t[j]) * 0.125f);
    qf[s] = t;
  }

  f32x4 oacc[4] = {};
  float mrow[4], lrow[4];
  #pragma unroll
  for (int r = 0; r < 4; ++r) { mrow[r] = -1e30f; lrow[r] = 0.0f; }

  const unsigned vs_base =
      (unsigned)(unsigned long long)(__attribute__((address_space(3))) u16*)Vs;
  char* pb = (char*)Ps + w * 2048;   // wave-private P tile (16 x 64 bf16)

  for (int kt = 0; kt < 32; ++kt) {
    const int kv0 = kt * 64;
    __syncthreads();
    #pragma unroll
    for (int r = 0; r < 2; ++r) {
      const int c = (r << 8) + (w << 6) + l;          // chunk 0..511
      // K: row-major [64][64], slots XOR-pre-swizzled at the global source
      const int krow = c >> 3, slot = c & 7;
      gload16(KV + (size_t)(b * 2048 + kv0 + krow) * 2048 + h * 64 + ((slot ^ (krow & 7)) << 3),
              &Ks[(size_t)((r << 8) + (w << 6)) * 8]);
      // V: subtiled [(d>>4)*16 + (kv>>2)][(kv&3)*16 + (d&15)]
      const int vkv = ((c >> 3) & 15) * 4 + ((c >> 1) & 3);
      const int vd0 = (c >> 7) * 16 + (c & 1) * 8;
      gload16(KV + (size_t)(b * 2048 + kv0 + vkv) * 2048 + 1024 + h * 64 + vd0,
              &Vs[(size_t)((r << 8) + (w << 6)) * 8]);
    }
    __syncthreads();

    // S = Q @ K^T  (16 x 64, f32)
    f32x4 sacc[4] = {};
    #pragma unroll
    for (int s = 0; s < 2; ++s)
      #pragma unroll
      for (int nf = 0; nf < 4; ++nf) {
        const int krw = nf * 16 + q;
        const s16x8 kf = *(const s16x8*)((const char*)Ks + krw * 128 +
                              ((s * 64 + g * 16) ^ ((krw & 7) << 4)));
        sacc[nf] = __builtin_amdgcn_mfma_f32_16x16x32_bf16(qf[s], kf, sacc[nf], 0, 0, 0);
      }

    // online softmax (rows = g*4 + r, cols spread over 16 lanes x 4 nf)
    float p[4][4];
    #pragma unroll
    for (int r = 0; r < 4; ++r) {
      float mx = fmaxf(fmaxf(sacc[0][r], sacc[1][r]), fmaxf(sacc[2][r], sacc[3][r]));
      mx = fmaxf(mx, __shfl_xor(mx, 1));
      mx = fmaxf(mx, __shfl_xor(mx, 2));
      mx = fmaxf(mx, __shfl_xor(mx, 4));
      mx = fmaxf(mx, __shfl_xor(mx, 8));
      const float mnew  = fmaxf(mrow[r], mx);
      const float alpha = __builtin_amdgcn_exp2f((mrow[r] - mnew) * LOG2E);
      float rs = 0.0f;
      #pragma unroll
      for (int nf = 0; nf < 4; ++nf) {
        const float e = __builtin_amdgcn_exp2f((sacc[nf][r] - mnew) * LOG2E);
        p[nf][r] = e; rs += e;
      }
      rs += __shfl_xor(rs, 1); rs += __shfl_xor(rs, 2);
      rs += __shfl_xor(rs, 4); rs += __shfl_xor(rs, 8);
      lrow[r] = lrow[r] * alpha + rs;
      mrow[r] = mnew;
      #pragma unroll
      for (int nf = 0; nf < 4; ++nf) oacc[nf][r] *= alpha;
    }

    // P -> LDS (bf16, XOR-swizzled rows), wave-private: no barrier needed
    #pragma unroll
    for (int r = 0; r < 4; ++r) {
      const int prow = g * 4 + r;
      #pragma unroll
      for (int nf = 0; nf < 4; ++nf)
        *(u16*)(pb + prow * 128 + ((((nf * 16 + q) << 1)) ^ ((prow & 7) << 4))) =
            f2bf(p[nf][r]);
    }

    // O += P @ V
    #pragma unroll
    for (int s = 0; s < 2; ++s) {
      const int o1 = s * 64 + g * 8;   // A-frag kv bytes: cols 32s+4g+{0..3}, +16
      const u32x2 pa  = *(const u32x2*)(pb + q * 128 + (o1 ^ ((q & 7) << 4)));
      const u32x2 pb2 = *(const u32x2*)(pb + q * 128 + (((o1 + 32)) ^ ((q & 7) << 4)));
      union { u32x4 u; s16x8 s8; } au;
      au.u[0] = pa[0]; au.u[1] = pa[1]; au.u[2] = pb2[0]; au.u[3] = pb2[1];
      #pragma unroll
      for (int nf = 0; nf < 4; ++nf) {
        // tr-read: lane gets 4 bf16 at addr + {0,32,64,96}B = kv, kv+1, kv+2, kv+3
        const unsigned a1 = vs_base + (unsigned)((nf * 16 + 8 * s + g) * 128 + 2 * q);
        u32x2 t1, t2;
        asm volatile("ds_read_b64_tr_b16 %0, %2\n\t"
                     "ds_read_b64_tr_b16 %1, %2 offset:512\n\t"
                     "s_waitcnt lgkmcnt(0)"
                     : "=&v"(t1), "=&v"(t2) : "v"(a1) : "memory");
        __builtin_amdgcn_sched_barrier(0);
        union { u32x4 u; s16x8 s8; } bu;
        bu.u[0] = t1[0]; bu.u[1] = t1[1]; bu.u[2] = t2[0]; bu.u[3] = t2[1];
        oacc[nf] = __builtin_amdgcn_mfma_f32_16x16x32_bf16(au.s8, bu.s8, oacc[nf], 0, 0, 0);
      }
    }
  }

  const size_t ob = (size_t)(b * 2048 + qt * 64 + w * 16) * 1024 + h * 64;
  #pragma unroll
  for (int r = 0; r < 4; ++r) {
    const float inv = 1.0f / lrow[r];
    #pragma unroll
    for (int nf = 0; nf < 4; ++nf)
      O[ob + (size_t)(g * 4 + r) * 1024 + nf * 16 + q] = f2bf(oacc[nf][r] * inv);
  }
}

// ---------------- launch ----------------
extern "C" void kernel_launch(void* const* d_in, const int* in_sizes, int n_in,
                              void* d_out, int out_size, void* d_ws, size_t ws_size,
                              hipStream_t stream)
{
  const float* q_x  = (const float*)d_in[0];
  const float* kv_x = (const float*)d_in[1];
  const float* Wq   = (const float*)d_in[2];
  const float* Wkv  = (const float*)d_in[3];
  const float* Wo   = (const float*)d_in[4];
  const float* bo   = (const float*)d_in[5];
  const float* lnqg = (const float*)d_in[6];
  const float* lnqb = (const float*)d_in[7];
  const float* lnkg = (const float*)d_in[8];
  const float* lnkb = (const float*)d_in[9];
  const float* W1   = (const float*)d_in[10];
  const float* b1   = (const float*)d_in[11];
  const float* W2   = (const float*)d_in[12];
  const float* b2   = (const float*)d_in[13];
  float* out = (float*)d_out;

  char* ws = (char*)d_ws;
  const size_t MB = 1024 * 1024;
  u16*   wq_b  = (u16*)  (ws +  0 * MB);   // 2 MB
  u16*   wkv_b = (u16*)  (ws +  2 * MB);   // 4 MB
  u16*   wo_b  = (u16*)  (ws +  6 * MB);   // 2 MB
  u16*   w1_b  = (u16*)  (ws +  8 * MB);   // 8 MB
  u16*   w2_b  = (u16*)  (ws + 16 * MB);   // 8 MB
  u16*   lnq   = (u16*)  (ws + 24 * MB);   // 8 MB
  u16*   lnk   = (u16*)  (ws + 32 * MB);   // 8 MB
  u16*   qp    = (u16*)  (ws + 40 * MB);   // 8 MB
  u16*   kvp   = (u16*)  (ws + 48 * MB);   // 16 MB
  u16*   ao    = (u16*)  (ws + 64 * MB);   // 8 MB
  float* xf    = (float*)(ws + 72 * MB);   // 16 MB
  u16*   xb    = (u16*)  (ws + 88 * MB);   // 8 MB
  u16*   hb    = (u16*)  (ws + 96 * MB);   // 32 MB -> 128 MB total

  cast_k<<<dim3(1024), dim3(256), 0, stream>>>(Wq,  wq_b,  1024 * 1024 / 4);
  cast_k<<<dim3(2048), dim3(256), 0, stream>>>(Wkv, wkv_b, 2048 * 1024 / 4);
  cast_k<<<dim3(1024), dim3(256), 0, stream>>>(Wo,  wo_b,  1024 * 1024 / 4);
  cast_k<<<dim3(4096), dim3(256), 0, stream>>>(W1,  w1_b,  4096 * 1024 / 4);
  cast_k<<<dim3(4096), dim3(256), 0, stream>>>(W2,  w2_b,  1024 * 4096 / 4);

  ln_cast_k<<<dim3(4096), dim3(256), 0, stream>>>(q_x,  lnqg, lnqb, lnq);
  ln_cast_k<<<dim3(4096), dim3(256), 0, stream>>>(kv_x, lnkg, lnkb, lnk);

  // q = LN(q_x) @ Wq^T
  gemm_bt<0,0,0,0,1><<<dim3(32 * 8),  dim3(256), 0, stream>>>(
      lnq, wq_b, qp, nullptr, nullptr, nullptr, 4096, 1024, 1024);
  // kv = LN(kv_x) @ Wkv^T
  gemm_bt<0,0,0,0,1><<<dim3(32 * 16), dim3(256), 0, stream>>>(
      lnk, wkv_b, kvp, nullptr, nullptr, nullptr, 4096, 2048, 1024);
  // flash attention
  attn_k<<<dim3(1024), dim3(256), 0, stream>>>(qp, kvp, ao);
  // x = q_x + ao @ Wo^T + bo   (store f32 + bf16)
  gemm_bt<1,1,0,1,1><<<dim3(32 * 8),  dim3(256), 0, stream>>>(
      ao, wo_b, xb, xf, bo, q_x, 4096, 1024, 1024);
  // h = silu(x @ W1^T + b1)
  gemm_bt<1,0,1,0,1><<<dim3(32 * 32), dim3(256), 0, stream>>>(
      xb, w1_b, hb, nullptr, b1, nullptr, 4096, 4096, 1024);
  // out = x + h @ W2^T + b2    (f32)
  gemm_bt<1,1,0,1,0><<<dim3(32 * 8),  dim3(256), 0, stream>>>(
      hb, w2_b, nullptr, out, b2, xf, 4096, 1024, 4096);
}

// Round 2
// 279.089 us; speedup vs baseline: 1.2108x; 1.2108x over previous
//
#include <hip/hip_runtime.h>

using u16   = unsigned short;
using f32x4 = __attribute__((ext_vector_type(4))) float;
using s16x8 = __attribute__((ext_vector_type(8))) short;
using u32x2 = __attribute__((ext_vector_type(2))) unsigned int;
using u32x4 = __attribute__((ext_vector_type(4))) unsigned int;

#define LOG2E 1.44269504088896f

static __device__ __forceinline__ u16 f2bf(float f) {
  union { float f; unsigned u; } a; a.f = f;
  unsigned r = a.u + 0x7fffu + ((a.u >> 16) & 1u);
  return (u16)(r >> 16);
}
static __device__ __forceinline__ float bf2f(u16 h) {
  union { unsigned u; float f; } a; a.u = ((unsigned)h) << 16; return a.f;
}
// pack two f32 -> u32 of 2 bf16 (lo = first arg), RNE
static __device__ __forceinline__ unsigned cvtpk(float lo, float hi) {
  unsigned r;
  asm("v_cvt_pk_bf16_f32 %0, %1, %2" : "=v"(r) : "v"(lo), "v"(hi));
  return r;
}

// global(16B per lane, per-lane src addr) -> LDS (wave-uniform base + lane*16)
static __device__ __forceinline__ void gload16(const void* g, void* l) {
  __builtin_amdgcn_global_load_lds(
      (__attribute__((address_space(1))) unsigned int*)g,
      (__attribute__((address_space(3))) unsigned int*)l, 16, 0, 0);
}

// ---------------- merged LayerNorm + cast to bf16 (row = 1024) ----------------
__global__ __launch_bounds__(256) void ln2_k(
    const float* __restrict__ xq, const float* __restrict__ xk,
    const float* __restrict__ gq, const float* __restrict__ bq,
    const float* __restrict__ gk, const float* __restrict__ bk,
    u16* __restrict__ oq, u16* __restrict__ ok)
{
  int row = blockIdx.x;
  const float* x; const float* gam; const float* bet; u16* out;
  if (row < 4096) { x = xq; gam = gq; bet = bq; out = oq; }
  else { row -= 4096; x = xk; gam = gk; bet = bk; out = ok; }
  const int t = threadIdx.x;
  const float4 v = ((const float4*)(x + (size_t)row * 1024))[t];
  float s  = v.x + v.y + v.z + v.w;
  float ss = v.x*v.x + v.y*v.y + v.z*v.z + v.w*v.w;
  #pragma unroll
  for (int m = 1; m < 64; m <<= 1) { s += __shfl_xor(s, m); ss += __shfl_xor(ss, m); }
  __shared__ float red[8];
  const int w = t >> 6;
  if ((t & 63) == 0) { red[w] = s; red[4 + w] = ss; }
  __syncthreads();
  s  = red[0] + red[1] + red[2] + red[3];
  ss = red[4] + red[5] + red[6] + red[7];
  const float mu   = s * (1.0f / 1024.0f);
  const float rstd = rsqrtf(ss * (1.0f / 1024.0f) - mu * mu + 1e-5f);
  const float4 gv = ((const float4*)gam)[t];
  const float4 bv = ((const float4*)bet)[t];
  ushort4 o;
  o.x = f2bf((v.x - mu) * rstd * gv.x + bv.x);
  o.y = f2bf((v.y - mu) * rstd * gv.y + bv.y);
  o.z = f2bf((v.z - mu) * rstd * gv.z + bv.z);
  o.w = f2bf((v.w - mu) * rstd * gv.w + bv.w);
  ((ushort4*)(out + (size_t)row * 1024))[t] = o;
}

// ---------------- all weight casts in one launch ----------------
__global__ __launch_bounds__(256) void cast_all_k(
    const float* __restrict__ Wq, const float* __restrict__ Wkv,
    const float* __restrict__ Wo, const float* __restrict__ W1,
    const float* __restrict__ W2,
    u16* __restrict__ wq_b, u16* __restrict__ wkv_b, u16* __restrict__ wo_b,
    u16* __restrict__ w1_b, u16* __restrict__ w2_b)
{
  const int i = blockIdx.x * 256 + threadIdx.x;   // float4-chunk id
  const float* src; u16* dst; int off;
  if      (i <  262144) { src = Wq;  dst = wq_b;  off = i; }
  else if (i <  786432) { src = Wkv; dst = wkv_b; off = i -  262144; }
  else if (i < 1048576) { src = Wo;  dst = wo_b;  off = i -  786432; }
  else if (i < 2097152) { src = W1;  dst = w1_b;  off = i - 1048576; }
  else                  { src = W2;  dst = w2_b;  off = i - 2097152; }
  const float4 v = ((const float4*)src)[off];
  ushort4 o;
  o.x = f2bf(v.x); o.y = f2bf(v.y); o.z = f2bf(v.z); o.w = f2bf(v.w);
  ((ushort4*)dst)[off] = o;
}

// ---------------- GEMM body: C[M,N] = A[M,K] @ B[N,K]^T, 2-phase dbuf ----------------
// 128x128 tile, 4 waves (2x2, each 64x64 = 4x4 frags of 16x16), BK=32.
template<int BIAS, int RES, int SILU, int OF32, int OBF>
static __device__ __forceinline__ void gemm_body(
    const u16* __restrict__ A, const u16* __restrict__ B,
    u16* __restrict__ Cb, float* __restrict__ Cf,
    const float* __restrict__ bias, const float* __restrict__ resid,
    int N, int K, int bid, u16* smem)
{
  const int tid = threadIdx.x;
  const int w = tid >> 6, l = tid & 63;
  const int g = l >> 4, q = l & 15;
  const int ntn = N >> 7;
  const int bm = bid / ntn, bn = bid - bm * ntn;
  const int wr = w >> 1, wc = w & 1;
  f32x4 acc[4][4] = {};

  const size_t abase = (size_t)(bm * 128) * K;
  const size_t bbase = (size_t)(bn * 128) * K;

  // smem: As[2][4096], Bs[2][4096]
  auto stage = [&](int buf, int k0) {
    u16* as = smem + buf * 4096;
    u16* bs = smem + 8192 + buf * 4096;
    #pragma unroll
    for (int r = 0; r < 2; ++r) {
      const int c = (r << 8) + tid;            // chunk 0..511 (16B each)
      const int row = c >> 2, part = c & 3;    // 128 rows x 4 parts (8 bf16)
      u16* ab = as + (size_t)((r << 8) + (w << 6)) * 8;   // wave-uniform dest
      u16* bb = bs + (size_t)((r << 8) + (w << 6)) * 8;
      gload16(A + abase + (size_t)row * K + k0 + part * 8, ab);
      gload16(B + bbase + (size_t)row * K + k0 + part * 8, bb);
    }
  };

  const int NT = K >> 5;
  stage(0, 0);
  __syncthreads();
  int cur = 0;
  for (int t = 0; t < NT; ++t) {
    if (t + 1 < NT) stage(cur ^ 1, (t + 1) << 5);
    const u16* as = smem + cur * 4096;
    const u16* bs = smem + 8192 + cur * 4096;
    s16x8 af[4], bfr[4];
    #pragma unroll
    for (int m = 0; m < 4; ++m)
      af[m] = *(const s16x8*)&as[(wr * 64 + m * 16 + q) * 32 + g * 8];
    #pragma unroll
    for (int n = 0; n < 4; ++n)
      bfr[n] = *(const s16x8*)&bs[(wc * 64 + n * 16 + q) * 32 + g * 8];
    #pragma unroll
    for (int m = 0; m < 4; ++m)
      #pragma unroll
      for (int n = 0; n < 4; ++n)
        acc[m][n] = __builtin_amdgcn_mfma_f32_16x16x32_bf16(af[m], bfr[n], acc[m][n], 0, 0, 0);
    asm volatile("s_waitcnt vmcnt(0)" ::: "memory");
    __syncthreads();
    cur ^= 1;
  }

  #pragma unroll
  for (int m = 0; m < 4; ++m) {
    const int row0 = bm * 128 + wr * 64 + m * 16 + g * 4;
    #pragma unroll
    for (int n = 0; n < 4; ++n) {
      const int col = bn * 128 + wc * 64 + n * 16 + q;
      float bv = 0.0f;
      if (BIAS) bv = bias[col];
      #pragma unroll
      for (int r = 0; r < 4; ++r) {
        const size_t idx = (size_t)(row0 + r) * N + col;
        float v = acc[m][n][r] + bv;
        if (RES)  v += resid[idx];
        if (SILU) v = v / (1.0f + __expf(-v));
        if (OF32) Cf[idx] = v;
        if (OBF)  Cb[idx] = f2bf(v);
      }
    }
  }
}

template<int BIAS, int RES, int SILU, int OF32, int OBF>
__global__ __launch_bounds__(256, 2) void gemm_k(
    const u16* __restrict__ A, const u16* __restrict__ B,
    u16* __restrict__ Cb, float* __restrict__ Cf,
    const float* __restrict__ bias, const float* __restrict__ resid,
    int N, int K)
{
  __shared__ u16 smem[16384];
  gemm_body<BIAS, RES, SILU, OF32, OBF>(A, B, Cb, Cf, bias, resid, N, K, blockIdx.x, smem);
}

// q-proj (blocks 0..255) and kv-proj (blocks 256..767) merged
__global__ __launch_bounds__(256, 2) void gemm_qkv_k(
    const u16* __restrict__ lnq, const u16* __restrict__ wq, u16* __restrict__ qp,
    const u16* __restrict__ lnk, const u16* __restrict__ wkv, u16* __restrict__ kvp)
{
  __shared__ u16 smem[16384];
  if (blockIdx.x < 256)
    gemm_body<0,0,0,0,1>(lnq, wq, qp, nullptr, nullptr, nullptr, 1024, 1024, blockIdx.x, smem);
  else
    gemm_body<0,0,0,0,1>(lnk, wkv, kvp, nullptr, nullptr, nullptr, 2048, 1024, blockIdx.x - 256, smem);
}

// ---------------- Flash attention (swapped QK^T, in-lane softmax) ----------------
// grid = bh*64 + qtile. 2 waves x 16 q-rows (Q-tile 32). KV-tile 64. HD=64.
// S^T = mfma(K,Q): lane (g,q) holds S[k=nf*16+g*4+r][qrow=q] -> softmax is
// mostly lane-local (2 shfl_xor for cross-g). P packed via v_cvt_pk_bf16_f32,
// staged to wave-private LDS [q][k] (XOR-swizzled) as 8 ds_write_b32.
__global__ __launch_bounds__(128, 4) void attn_k(
    const u16* __restrict__ Q, const u16* __restrict__ KV, u16* __restrict__ O)
{
  __shared__ u16 Ks[64 * 64];
  __shared__ u16 Vs[64 * 64];
  __shared__ u16 Ps[2 * 16 * 64];
  const int tid = threadIdx.x;
  const int w = tid >> 6, l = tid & 63;
  const int g = l >> 4, q = l & 15;
  const int bh = blockIdx.x >> 6, qt = blockIdx.x & 63;
  const int b = bh >> 4, h = bh & 15;
  const int sw = (q & 7) << 4;

  // Q fragments (16 rows x 64), pre-scaled by 1/8 (exact in bf16)
  const size_t qrow = (size_t)(b * 2048 + qt * 32 + w * 16 + q);
  s16x8 qf[2];
  #pragma unroll
  for (int s = 0; s < 2; ++s) {
    s16x8 t = *(const s16x8*)&Q[qrow * 1024 + h * 64 + s * 32 + g * 8];
    #pragma unroll
    for (int j = 0; j < 8; ++j)
      t[j] = (short)f2bf(bf2f((u16)t[j]) * 0.125f);
    qf[s] = t;
  }

  f32x4 oacc[4] = {};
  float mrow = -1e30f, lrow = 0.0f;

  const unsigned vs_base =
      (unsigned)(unsigned long long)(__attribute__((address_space(3))) u16*)Vs;
  char* pb = (char*)Ps + w * 2048;   // wave-private P tile (16 x 64 bf16)

  for (int kt = 0; kt < 32; ++kt) {
    const int kv0 = kt * 64;
    __syncthreads();
    #pragma unroll
    for (int r = 0; r < 4; ++r) {
      const int c = (r << 7) + tid;                   // chunk 0..511
      // K: row-major [64][64], 16B slots XOR-pre-swizzled at the global source
      const int krow = c >> 3, slot = c & 7;
      gload16(KV + (size_t)(b * 2048 + kv0 + krow) * 2048 + h * 64 + ((slot ^ (krow & 7)) << 3),
              Ks + (size_t)((r << 7) + (w << 6)) * 8);
      // V: subtiled [(d>>4)*16 + (kv>>2)][(kv&3)*16 + (d&15)] for tr_b16 reads
      const int vkv = ((c >> 3) & 15) * 4 + ((c >> 1) & 3);
      const int vd0 = ((c >> 7) & 3) * 16 + (c & 1) * 8;
      gload16(KV + (size_t)(b * 2048 + kv0 + vkv) * 2048 + 1024 + h * 64 + vd0,
              Vs + (size_t)((r << 7) + (w << 6)) * 8);
    }
    __syncthreads();

    // S^T = K @ Q^T: sacc[nf] reg r = S[k = nf*16 + g*4 + r][qrow = q]
    f32x4 sacc[4] = {};
    #pragma unroll
    for (int s = 0; s < 2; ++s)
      #pragma unroll
      for (int nf = 0; nf < 4; ++nf) {
        const int krw = nf * 16 + q;
        const s16x8 kf = *(const s16x8*)((const char*)Ks + krw * 128 +
                              ((s * 64 + g * 16) ^ ((krw & 7) << 4)));
        sacc[nf] = __builtin_amdgcn_mfma_f32_16x16x32_bf16(kf, qf[s], sacc[nf], 0, 0, 0);
      }

    // per-lane softmax over this lane's 16 k-values, then 2 shfl_xor across g
    float mx = sacc[0][0];
    #pragma unroll
    for (int nf = 0; nf < 4; ++nf)
      #pragma unroll
      for (int r = 0; r < 4; ++r) mx = fmaxf(mx, sacc[nf][r]);
    mx = fmaxf(mx, __shfl_xor(mx, 16));
    mx = fmaxf(mx, __shfl_xor(mx, 32));
    if (__any(mx > mrow + 8.0f)) {          // defer-max (T13, THR=8)
      const float mnew = fmaxf(mrow, mx);
      const float al = __builtin_amdgcn_exp2f((mrow - mnew) * LOG2E);
      lrow *= al;
      float ar[4];
      #pragma unroll
      for (int r = 0; r < 4; ++r) ar[r] = __shfl(al, g * 4 + r);
      #pragma unroll
      for (int nf = 0; nf < 4; ++nf)
        #pragma unroll
        for (int r = 0; r < 4; ++r) oacc[nf][r] *= ar[r];
      mrow = mnew;
    }
    float rs = 0.0f;
    #pragma unroll
    for (int nf = 0; nf < 4; ++nf)
      #pragma unroll
      for (int r = 0; r < 4; ++r) {
        const float e = __builtin_amdgcn_exp2f((sacc[nf][r] - mrow) * LOG2E);
        sacc[nf][r] = e; rs += e;
      }
    rs += __shfl_xor(rs, 16);
    rs += __shfl_xor(rs, 32);
    lrow += rs;

    // P -> LDS: lane holds P[k = nf*16 + g*4 + {0..3}][q]; pack pairs, write
    // u32 at row q, byte (32nf + 8g + 4h) ^ sw. Wave-private: no barrier.
    #pragma unroll
    for (int nf = 0; nf < 4; ++nf) {
      const unsigned w0 = cvtpk(sacc[nf][0], sacc[nf][1]);
      const unsigned w1 = cvtpk(sacc[nf][2], sacc[nf][3]);
      *(unsigned*)(pb + q * 128 + ((32 * nf + 8 * g    ) ^ sw)) = w0;
      *(unsigned*)(pb + q * 128 + ((32 * nf + 8 * g + 4) ^ sw)) = w1;
    }

    // O += P @ V
    #pragma unroll
    for (int s = 0; s < 2; ++s) {
      const int o1 = s * 64 + g * 8;   // A-frag kv bytes: k = 32s+4g+{0..3}, +16
      const u32x2 pa  = *(const u32x2*)(pb + q * 128 + (o1 ^ sw));
      const u32x2 pb2 = *(const u32x2*)(pb + q * 128 + ((o1 + 32) ^ sw));
      union { u32x4 u; s16x8 s8; } au;
      au.u[0] = pa[0]; au.u[1] = pa[1]; au.u[2] = pb2[0]; au.u[3] = pb2[1];
      #pragma unroll
      for (int nf = 0; nf < 4; ++nf) {
        // tr-read: lane gets 4 bf16 at addr + {0,32,64,96}B = kv, kv+1, kv+2, kv+3
        const unsigned a1 = vs_base + (unsigned)((nf * 16 + 8 * s + g) * 128 + 2 * q);
        u32x2 t1, t2;
        asm volatile("ds_read_b64_tr_b16 %0, %2\n\t"
                     "ds_read_b64_tr_b16 %1, %2 offset:512\n\t"
                     "s_waitcnt lgkmcnt(0)"
                     : "=&v"(t1), "=&v"(t2) : "v"(a1) : "memory");
        __builtin_amdgcn_sched_barrier(0);
        union { u32x4 u; s16x8 s8; } bu;
        bu.u[0] = t1[0]; bu.u[1] = t1[1]; bu.u[2] = t2[0]; bu.u[3] = t2[1];
        oacc[nf] = __builtin_amdgcn_mfma_f32_16x16x32_bf16(au.s8, bu.s8, oacc[nf], 0, 0, 0);
      }
    }
  }

  float lr[4];
  #pragma unroll
  for (int r = 0; r < 4; ++r) lr[r] = __shfl(lrow, g * 4 + r);
  const size_t ob = (size_t)(b * 2048 + qt * 32 + w * 16) * 1024 + h * 64;
  #pragma unroll
  for (int r = 0; r < 4; ++r) {
    const float inv = 1.0f / lr[r];
    #pragma unroll
    for (int nf = 0; nf < 4; ++nf)
      O[ob + (size_t)(g * 4 + r) * 1024 + nf * 16 + q] = f2bf(oacc[nf][r] * inv);
  }
}

// ---------------- launch ----------------
extern "C" void kernel_launch(void* const* d_in, const int* in_sizes, int n_in,
                              void* d_out, int out_size, void* d_ws, size_t ws_size,
                              hipStream_t stream)
{
  const float* q_x  = (const float*)d_in[0];
  const float* kv_x = (const float*)d_in[1];
  const float* Wq   = (const float*)d_in[2];
  const float* Wkv  = (const float*)d_in[3];
  const float* Wo   = (const float*)d_in[4];
  const float* bo   = (const float*)d_in[5];
  const float* lnqg = (const float*)d_in[6];
  const float* lnqb = (const float*)d_in[7];
  const float* lnkg = (const float*)d_in[8];
  const float* lnkb = (const float*)d_in[9];
  const float* W1   = (const float*)d_in[10];
  const float* b1   = (const float*)d_in[11];
  const float* W2   = (const float*)d_in[12];
  const float* b2   = (const float*)d_in[13];
  float* out = (float*)d_out;

  char* ws = (char*)d_ws;
  const size_t MB = 1024 * 1024;
  u16*   wq_b  = (u16*)  (ws +  0 * MB);   // 2 MB
  u16*   wkv_b = (u16*)  (ws +  2 * MB);   // 4 MB
  u16*   wo_b  = (u16*)  (ws +  6 * MB);   // 2 MB
  u16*   w1_b  = (u16*)  (ws +  8 * MB);   // 8 MB
  u16*   w2_b  = (u16*)  (ws + 16 * MB);   // 8 MB
  u16*   lnq   = (u16*)  (ws + 24 * MB);   // 8 MB
  u16*   lnk   = (u16*)  (ws + 32 * MB);   // 8 MB
  u16*   qp    = (u16*)  (ws + 40 * MB);   // 8 MB
  u16*   kvp   = (u16*)  (ws + 48 * MB);   // 16 MB
  u16*   ao    = (u16*)  (ws + 64 * MB);   // 8 MB
  float* xf    = (float*)(ws + 72 * MB);   // 16 MB
  u16*   xb    = (u16*)  (ws + 88 * MB);   // 8 MB
  u16*   hb    = (u16*)  (ws + 96 * MB);   // 32 MB -> 128 MB total

  cast_all_k<<<dim3(12288), dim3(256), 0, stream>>>(
      Wq, Wkv, Wo, W1, W2, wq_b, wkv_b, wo_b, w1_b, w2_b);
  ln2_k<<<dim3(8192), dim3(256), 0, stream>>>(
      q_x, kv_x, lnqg, lnqb, lnkg, lnkb, lnq, lnk);

  // q = LN(q_x) @ Wq^T ; kv = LN(kv_x) @ Wkv^T (merged)
  gemm_qkv_k<<<dim3(768), dim3(256), 0, stream>>>(lnq, wq_b, qp, lnk, wkv_b, kvp);
  // flash attention
  attn_k<<<dim3(2048), dim3(128), 0, stream>>>(qp, kvp, ao);
  // x = q_x + ao @ Wo^T + bo   (store f32 + bf16)
  gemm_k<1,1,0,1,1><<<dim3(256),  dim3(256), 0, stream>>>(
      ao, wo_b, xb, xf, bo, q_x, 1024, 1024);
  // h = silu(x @ W1^T + b1)
  gemm_k<1,0,1,0,1><<<dim3(1024), dim3(256), 0, stream>>>(
      xb, w1_b, hb, nullptr, b1, nullptr, 4096, 1024);
  // out = x + h @ W2^T + b2    (f32)
  gemm_k<1,1,0,1,0><<<dim3(256),  dim3(256), 0, stream>>>(
      hb, w2_b, nullptr, out, b2, xf, 1024, 4096);
}

// Round 3
// 236.924 us; speedup vs baseline: 1.4262x; 1.1780x over previous
//
#include <hip/hip_runtime.h>

using u16   = unsigned short;
using f32x4 = __attribute__((ext_vector_type(4))) float;
using s16x8 = __attribute__((ext_vector_type(8))) short;
using u32x2 = __attribute__((ext_vector_type(2))) unsigned int;
using u32x4 = __attribute__((ext_vector_type(4))) unsigned int;

#define LOG2E 1.44269504088896f

static __device__ __forceinline__ u16 f2bf(float f) {
  union { float f; unsigned u; } a; a.f = f;
  unsigned r = a.u + 0x7fffu + ((a.u >> 16) & 1u);
  return (u16)(r >> 16);
}
// pack two f32 -> u32 of 2 bf16 (lo = first arg), RNE
static __device__ __forceinline__ unsigned cvtpk(float lo, float hi) {
  unsigned r;
  asm("v_cvt_pk_bf16_f32 %0, %1, %2" : "=v"(r) : "v"(lo), "v"(hi));
  return r;
}

// global(16B per lane, per-lane src addr) -> LDS (wave-uniform base + lane*16)
static __device__ __forceinline__ void gload16(const void* g, void* l) {
  __builtin_amdgcn_global_load_lds(
      (__attribute__((address_space(1))) unsigned int*)g,
      (__attribute__((address_space(3))) unsigned int*)l, 16, 0, 0);
}

// ---------------- merged LayerNorm + cast to bf16 (row = 1024) ----------------
__global__ __launch_bounds__(256) void ln2_k(
    const float* __restrict__ xq, const float* __restrict__ xk,
    const float* __restrict__ gq, const float* __restrict__ bq,
    const float* __restrict__ gk, const float* __restrict__ bk,
    u16* __restrict__ oq, u16* __restrict__ ok)
{
  int row = blockIdx.x;
  const float* x; const float* gam; const float* bet; u16* out;
  if (row < 4096) { x = xq; gam = gq; bet = bq; out = oq; }
  else { row -= 4096; x = xk; gam = gk; bet = bk; out = ok; }
  const int t = threadIdx.x;
  const float4 v = ((const float4*)(x + (size_t)row * 1024))[t];
  float s  = v.x + v.y + v.z + v.w;
  float ss = v.x*v.x + v.y*v.y + v.z*v.z + v.w*v.w;
  #pragma unroll
  for (int m = 1; m < 64; m <<= 1) { s += __shfl_xor(s, m); ss += __shfl_xor(ss, m); }
  __shared__ float red[8];
  const int w = t >> 6;
  if ((t & 63) == 0) { red[w] = s; red[4 + w] = ss; }
  __syncthreads();
  s  = red[0] + red[1] + red[2] + red[3];
  ss = red[4] + red[5] + red[6] + red[7];
  const float mu   = s * (1.0f / 1024.0f);
  const float rstd = rsqrtf(ss * (1.0f / 1024.0f) - mu * mu + 1e-5f);
  const float4 gv = ((const float4*)gam)[t];
  const float4 bv = ((const float4*)bet)[t];
  ushort4 o;
  o.x = f2bf((v.x - mu) * rstd * gv.x + bv.x);
  o.y = f2bf((v.y - mu) * rstd * gv.y + bv.y);
  o.z = f2bf((v.z - mu) * rstd * gv.z + bv.z);
  o.w = f2bf((v.w - mu) * rstd * gv.w + bv.w);
  ((ushort4*)(out + (size_t)row * 1024))[t] = o;
}

// ---------------- all weight casts in one launch (Wq pre-scaled by 1/8) ----------------
__global__ __launch_bounds__(256) void cast_all_k(
    const float* __restrict__ Wq, const float* __restrict__ Wkv,
    const float* __restrict__ Wo, const float* __restrict__ W1,
    const float* __restrict__ W2,
    u16* __restrict__ wq_b, u16* __restrict__ wkv_b, u16* __restrict__ wo_b,
    u16* __restrict__ w1_b, u16* __restrict__ w2_b)
{
  const int i = blockIdx.x * 256 + threadIdx.x;   // float4-chunk id
  const float* src; u16* dst; int off; float sc = 1.0f;
  if      (i <  262144) { src = Wq;  dst = wq_b;  off = i; sc = 0.125f; }
  else if (i <  786432) { src = Wkv; dst = wkv_b; off = i -  262144; }
  else if (i < 1048576) { src = Wo;  dst = wo_b;  off = i -  786432; }
  else if (i < 2097152) { src = W1;  dst = w1_b;  off = i - 1048576; }
  else                  { src = W2;  dst = w2_b;  off = i - 2097152; }
  const float4 v = ((const float4*)src)[off];
  ushort4 o;
  o.x = f2bf(v.x * sc); o.y = f2bf(v.y * sc); o.z = f2bf(v.z * sc); o.w = f2bf(v.w * sc);
  ((ushort4*)dst)[off] = o;
}

// ---------------- GEMM: C[M,N] = A[M,K] @ B[N,K]^T ----------------
// 128x128 tile, 512 threads / 8 waves (4 wr x 2 wc, wave = 32x64 = 2x4 frags),
// BK=64, double-buffered, T2 XOR-swizzled LDS (pre-swizzled global source).
template<int BIAS, int RES, int SILU, int OF32, int OBF>
static __device__ __forceinline__ void gemm_body(
    const u16* __restrict__ A, const u16* __restrict__ B,
    u16* __restrict__ Cb, float* __restrict__ Cf,
    const float* __restrict__ bias, const float* __restrict__ resid,
    int N, int K, int bid, u16* smem)
{
  const int tid = threadIdx.x;
  const int w = tid >> 6, l = tid & 63;
  const int g = l >> 4, q = l & 15;
  const int ntn = N >> 7;
  const int bm = bid / ntn, bn = bid - bm * ntn;
  const int wr = w >> 1, wc = w & 1;
  const int sw = (q & 7) << 4;
  f32x4 acc[2][4] = {};

  const size_t abase = (size_t)(bm * 128) * K;
  const size_t bbase = (size_t)(bn * 128) * K;

  // smem: A[2][128*64], B[2][128*64] u16 (64 KB total)
  auto stage = [&](int buf, int k0) {
    u16* as = smem + buf * 8192;
    u16* bs = smem + 16384 + buf * 8192;
    #pragma unroll
    for (int r = 0; r < 2; ++r) {
      const int c = (r << 9) + tid;            // chunk 0..1023 (16B each)
      const int row = c >> 3, part = c & 7;    // 128 rows x 8 parts
      const int sp = part ^ (row & 7);         // inverse-swizzled source part
      gload16(A + abase + (size_t)row * K + k0 + sp * 8,
              as + (size_t)((r << 9) + (w << 6)) * 8);
      gload16(B + bbase + (size_t)row * K + k0 + sp * 8,
              bs + (size_t)((r << 9) + (w << 6)) * 8);
    }
  };

  const int NT = K >> 6;
  stage(0, 0);
  asm volatile("s_waitcnt vmcnt(0)" ::: "memory");
  __syncthreads();
  int cur = 0;
  for (int t = 0; t < NT; ++t) {
    if (t + 1 < NT) stage(cur ^ 1, (t + 1) << 6);
    const char* as = (const char*)(smem + cur * 8192);
    const char* bs = (const char*)(smem + 16384 + cur * 8192);
    #pragma unroll
    for (int ks = 0; ks < 2; ++ks) {
      s16x8 af[2], bfr[4];
      #pragma unroll
      for (int m = 0; m < 2; ++m)
        af[m] = *(const s16x8*)(as + (size_t)(wr * 32 + m * 16 + q) * 128 +
                                ((ks * 64 + g * 16) ^ sw));
      #pragma unroll
      for (int n = 0; n < 4; ++n)
        bfr[n] = *(const s16x8*)(bs + (size_t)(wc * 64 + n * 16 + q) * 128 +
                                 ((ks * 64 + g * 16) ^ sw));
      #pragma unroll
      for (int m = 0; m < 2; ++m)
        #pragma unroll
        for (int n = 0; n < 4; ++n)
          acc[m][n] = __builtin_amdgcn_mfma_f32_16x16x32_bf16(af[m], bfr[n], acc[m][n], 0, 0, 0);
    }
    asm volatile("s_waitcnt vmcnt(0)" ::: "memory");
    __syncthreads();
    cur ^= 1;
  }

  #pragma unroll
  for (int m = 0; m < 2; ++m) {
    const int row0 = bm * 128 + wr * 32 + m * 16 + g * 4;
    #pragma unroll
    for (int n = 0; n < 4; ++n) {
      const int col = bn * 128 + wc * 64 + n * 16 + q;
      float bv = 0.0f;
      if (BIAS) bv = bias[col];
      #pragma unroll
      for (int r = 0; r < 4; ++r) {
        const size_t idx = (size_t)(row0 + r) * N + col;
        float v = acc[m][n][r] + bv;
        if (RES)  v += resid[idx];
        if (SILU) v = v / (1.0f + __expf(-v));
        if (OF32) Cf[idx] = v;
        if (OBF)  Cb[idx] = f2bf(v);
      }
    }
  }
}

template<int BIAS, int RES, int SILU, int OF32, int OBF>
__global__ __launch_bounds__(512, 4) void gemm_k(
    const u16* __restrict__ A, const u16* __restrict__ B,
    u16* __restrict__ Cb, float* __restrict__ Cf,
    const float* __restrict__ bias, const float* __restrict__ resid,
    int N, int K)
{
  __shared__ u16 smem[32768];
  gemm_body<BIAS, RES, SILU, OF32, OBF>(A, B, Cb, Cf, bias, resid, N, K, blockIdx.x, smem);
}

// q-proj (blocks 0..255) and kv-proj (blocks 256..767) merged
__global__ __launch_bounds__(512, 4) void gemm_qkv_k(
    const u16* __restrict__ lnq, const u16* __restrict__ wq, u16* __restrict__ qp,
    const u16* __restrict__ lnk, const u16* __restrict__ wkv, u16* __restrict__ kvp)
{
  __shared__ u16 smem[32768];
  if (blockIdx.x < 256)
    gemm_body<0,0,0,0,1>(lnq, wq, qp, nullptr, nullptr, nullptr, 1024, 1024, blockIdx.x, smem);
  else
    gemm_body<0,0,0,0,1>(lnk, wkv, kvp, nullptr, nullptr, nullptr, 2048, 1024, blockIdx.x - 256, smem);
}

// ---------------- Flash attention (swapped QK^T, dbuf K/V, Q-tile 64) ----------------
// grid = bh*32 + qtile. 4 waves x 16 q-rows. KV-tile 64, double-buffered.
// S^T = mfma(K,Q): lane (g,q) holds S[k=nf*16+g*4+r][qrow=q] -> softmax is
// mostly lane-local (2 shfl_xor). P packed via v_cvt_pk_bf16_f32 to
// wave-private swizzled LDS. V consumed via ds_read_b64_tr_b16.
// Q arrives pre-scaled by 1/8 (folded into Wq cast).
__global__ __launch_bounds__(256, 4) void attn_k(
    const u16* __restrict__ Q, const u16* __restrict__ KV, u16* __restrict__ O)
{
  __shared__ u16 Ks[2][64 * 64];
  __shared__ u16 Vs[2][64 * 64];
  __shared__ u16 Ps[4][16 * 64];
  const int tid = threadIdx.x;
  const int w = tid >> 6, l = tid & 63;
  const int g = l >> 4, q = l & 15;
  const int bh = blockIdx.x >> 5, qt = blockIdx.x & 31;
  const int b = bh >> 4, h = bh & 15;
  const int sw = (q & 7) << 4;

  // Q fragments (this wave's 16 rows x 64)
  const size_t qrow = (size_t)(b * 2048 + qt * 64 + w * 16 + q);
  s16x8 qf[2];
  qf[0] = *(const s16x8*)&Q[qrow * 1024 + h * 64 + g * 8];
  qf[1] = *(const s16x8*)&Q[qrow * 1024 + h * 64 + 32 + g * 8];

  f32x4 oacc[4] = {};
  float mrow = -1e30f, lrow = 0.0f;

  const u16* kvb = KV + (size_t)b * 2048 * 2048;
  const unsigned vs_base =
      (unsigned)(unsigned long long)(__attribute__((address_space(3))) u16*)Vs;
  char* pb = (char*)Ps + w * 2048;   // wave-private P tile (16 x 64 bf16)

  auto stage = [&](int buf, int kv0) {
    #pragma unroll
    for (int r = 0; r < 2; ++r) {
      const int c = (r << 8) + tid;                   // chunk 0..511
      // K: row-major [64][64], 16B slots XOR-pre-swizzled at the global source
      const int krow = c >> 3, slot = c & 7;
      gload16(kvb + (size_t)(kv0 + krow) * 2048 + h * 64 + ((slot ^ (krow & 7)) << 3),
              &Ks[buf][(size_t)((r << 8) + (w << 6)) * 8]);
      // V: subtiled [(d>>4)*16 + (kv>>2)][(kv&3)*16 + (d&15)] for tr_b16 reads
      const int vkv = ((c >> 3) & 15) * 4 + ((c >> 1) & 3);
      const int vd0 = ((c >> 7) & 3) * 16 + (c & 1) * 8;
      gload16(kvb + (size_t)(kv0 + vkv) * 2048 + 1024 + h * 64 + vd0,
              &Vs[buf][(size_t)((r << 8) + (w << 6)) * 8]);
    }
  };

  stage(0, 0);
  asm volatile("s_waitcnt vmcnt(0)" ::: "memory");
  __syncthreads();
  int cur = 0;

  for (int kt = 0; kt < 32; ++kt) {
    if (kt + 1 < 32) stage(cur ^ 1, (kt + 1) * 64);

    // S^T = K @ Q^T: sacc[nf] reg r = S[k = nf*16 + g*4 + r][qrow = q]
    const char* ksb = (const char*)Ks[cur];
    f32x4 sacc[4] = {};
    #pragma unroll
    for (int s = 0; s < 2; ++s)
      #pragma unroll
      for (int nf = 0; nf < 4; ++nf) {
        const int krw = nf * 16 + q;
        const s16x8 kf = *(const s16x8*)(ksb + krw * 128 +
                              ((s * 64 + g * 16) ^ ((krw & 7) << 4)));
        sacc[nf] = __builtin_amdgcn_mfma_f32_16x16x32_bf16(kf, qf[s], sacc[nf], 0, 0, 0);
      }

    // per-lane softmax over this lane's 16 k-values, then 2 shfl_xor across g
    float mx = sacc[0][0];
    #pragma unroll
    for (int nf = 0; nf < 4; ++nf)
      #pragma unroll
      for (int r = 0; r < 4; ++r) mx = fmaxf(mx, sacc[nf][r]);
    mx = fmaxf(mx, __shfl_xor(mx, 16));
    mx = fmaxf(mx, __shfl_xor(mx, 32));
    if (__any(mx > mrow + 8.0f)) {          // defer-max (T13, THR=8)
      const float mnew = fmaxf(mrow, mx);
      const float al = __builtin_amdgcn_exp2f((mrow - mnew) * LOG2E);
      lrow *= al;
      float ar[4];
      #pragma unroll
      for (int r = 0; r < 4; ++r) ar[r] = __shfl(al, g * 4 + r);
      #pragma unroll
      for (int nf = 0; nf < 4; ++nf)
        #pragma unroll
        for (int r = 0; r < 4; ++r) oacc[nf][r] *= ar[r];
      mrow = mnew;
    }
    float rs = 0.0f;
    #pragma unroll
    for (int nf = 0; nf < 4; ++nf)
      #pragma unroll
      for (int r = 0; r < 4; ++r) {
        const float e = __builtin_amdgcn_exp2f((sacc[nf][r] - mrow) * LOG2E);
        sacc[nf][r] = e; rs += e;
      }
    rs += __shfl_xor(rs, 16);
    rs += __shfl_xor(rs, 32);
    lrow += rs;

    // P -> LDS: lane holds P[k = nf*16 + g*4 + {0..3}][q]; pack pairs, write
    // u32 at row q, swizzled. Wave-private: no barrier.
    #pragma unroll
    for (int nf = 0; nf < 4; ++nf) {
      const unsigned w0 = cvtpk(sacc[nf][0], sacc[nf][1]);
      const unsigned w1 = cvtpk(sacc[nf][2], sacc[nf][3]);
      *(unsigned*)(pb + q * 128 + ((32 * nf + 8 * g    ) ^ sw)) = w0;
      *(unsigned*)(pb + q * 128 + ((32 * nf + 8 * g + 4) ^ sw)) = w1;
    }

    // O += P @ V
    const unsigned vsb = vs_base + (unsigned)(cur << 13);
    #pragma unroll
    for (int s = 0; s < 2; ++s) {
      const int o1 = s * 64 + g * 8;   // A-frag kv bytes: k = 32s+4g+{0..3}, +16
      const u32x2 pa  = *(const u32x2*)(pb + q * 128 + (o1 ^ sw));
      const u32x2 pb2 = *(const u32x2*)(pb + q * 128 + ((o1 + 32) ^ sw));
      union { u32x4 u; s16x8 s8; } au;
      au.u[0] = pa[0]; au.u[1] = pa[1]; au.u[2] = pb2[0]; au.u[3] = pb2[1];
      #pragma unroll
      for (int nf = 0; nf < 4; ++nf) {
        // tr-read: lane gets 4 bf16 at addr + {0,32,64,96}B = kv, kv+1, kv+2, kv+3
        const unsigned a1 = vsb + (unsigned)((nf * 16 + 8 * s + g) * 128 + 2 * q);
        u32x2 t1, t2;
        asm volatile("ds_read_b64_tr_b16 %0, %2\n\t"
                     "ds_read_b64_tr_b16 %1, %2 offset:512\n\t"
                     "s_waitcnt lgkmcnt(0)"
                     : "=&v"(t1), "=&v"(t2) : "v"(a1) : "memory");
        __builtin_amdgcn_sched_barrier(0);
        union { u32x4 u; s16x8 s8; } bu;
        bu.u[0] = t1[0]; bu.u[1] = t1[1]; bu.u[2] = t2[0]; bu.u[3] = t2[1];
        oacc[nf] = __builtin_amdgcn_mfma_f32_16x16x32_bf16(au.s8, bu.s8, oacc[nf], 0, 0, 0);
      }
    }

    asm volatile("s_waitcnt vmcnt(0)" ::: "memory");
    __syncthreads();
    cur ^= 1;
  }

  float lr[4];
  #pragma unroll
  for (int r = 0; r < 4; ++r) lr[r] = __shfl(lrow, g * 4 + r);
  const size_t ob = (size_t)(b * 2048 + qt * 64 + w * 16) * 1024 + h * 64;
  #pragma unroll
  for (int r = 0; r < 4; ++r) {
    const float inv = 1.0f / lr[r];
    #pragma unroll
    for (int nf = 0; nf < 4; ++nf)
      O[ob + (size_t)(g * 4 + r) * 1024 + nf * 16 + q] = f2bf(oacc[nf][r] * inv);
  }
}

// ---------------- launch ----------------
extern "C" void kernel_launch(void* const* d_in, const int* in_sizes, int n_in,
                              void* d_out, int out_size, void* d_ws, size_t ws_size,
                              hipStream_t stream)
{
  const float* q_x  = (const float*)d_in[0];
  const float* kv_x = (const float*)d_in[1];
  const float* Wq   = (const float*)d_in[2];
  const float* Wkv  = (const float*)d_in[3];
  const float* Wo   = (const float*)d_in[4];
  const float* bo   = (const float*)d_in[5];
  const float* lnqg = (const float*)d_in[6];
  const float* lnqb = (const float*)d_in[7];
  const float* lnkg = (const float*)d_in[8];
  const float* lnkb = (const float*)d_in[9];
  const float* W1   = (const float*)d_in[10];
  const float* b1   = (const float*)d_in[11];
  const float* W2   = (const float*)d_in[12];
  const float* b2   = (const float*)d_in[13];
  float* out = (float*)d_out;

  char* ws = (char*)d_ws;
  const size_t MB = 1024 * 1024;
  u16*   wq_b  = (u16*)  (ws +  0 * MB);   // 2 MB
  u16*   wkv_b = (u16*)  (ws +  2 * MB);   // 4 MB
  u16*   wo_b  = (u16*)  (ws +  6 * MB);   // 2 MB
  u16*   w1_b  = (u16*)  (ws +  8 * MB);   // 8 MB
  u16*   w2_b  = (u16*)  (ws + 16 * MB);   // 8 MB
  u16*   lnq   = (u16*)  (ws + 24 * MB);   // 8 MB
  u16*   lnk   = (u16*)  (ws + 32 * MB);   // 8 MB
  u16*   qp    = (u16*)  (ws + 40 * MB);   // 8 MB
  u16*   kvp   = (u16*)  (ws + 48 * MB);   // 16 MB
  u16*   ao    = (u16*)  (ws + 64 * MB);   // 8 MB
  float* xf    = (float*)(ws + 72 * MB);   // 16 MB
  u16*   xb    = (u16*)  (ws + 88 * MB);   // 8 MB
  u16*   hb    = (u16*)  (ws + 96 * MB);   // 32 MB -> 128 MB total

  cast_all_k<<<dim3(12288), dim3(256), 0, stream>>>(
      Wq, Wkv, Wo, W1, W2, wq_b, wkv_b, wo_b, w1_b, w2_b);
  ln2_k<<<dim3(8192), dim3(256), 0, stream>>>(
      q_x, kv_x, lnqg, lnqb, lnkg, lnkb, lnq, lnk);

  // q = LN(q_x) @ (Wq/8)^T ; kv = LN(kv_x) @ Wkv^T (merged)
  gemm_qkv_k<<<dim3(768), dim3(512), 0, stream>>>(lnq, wq_b, qp, lnk, wkv_b, kvp);
  // flash attention
  attn_k<<<dim3(1024), dim3(256), 0, stream>>>(qp, kvp, ao);
  // x = q_x + ao @ Wo^T + bo   (store f32 + bf16)
  gemm_k<1,1,0,1,1><<<dim3(256),  dim3(512), 0, stream>>>(
      ao, wo_b, xb, xf, bo, q_x, 1024, 1024);
  // h = silu(x @ W1^T + b1)
  gemm_k<1,0,1,0,1><<<dim3(1024), dim3(512), 0, stream>>>(
      xb, w1_b, hb, nullptr, b1, nullptr, 4096, 1024);
  // out = x + h @ W2^T + b2    (f32)
  gemm_k<1,1,0,1,0><<<dim3(256),  dim3(512), 0, stream>>>(
      hb, w2_b, nullptr, out, b2, xf, 1024, 4096);
}

// Round 4
// 226.802 us; speedup vs baseline: 1.4899x; 1.0446x over previous
//
#include <hip/hip_runtime.h>

using u16   = unsigned short;
using f32x4 = __attribute__((ext_vector_type(4))) float;
using s16x8 = __attribute__((ext_vector_type(8))) short;
using u32x2 = __attribute__((ext_vector_type(2))) unsigned int;
using u32x4 = __attribute__((ext_vector_type(4))) unsigned int;

#define LOG2E 1.44269504088896f

static __device__ __forceinline__ u16 f2bf(float f) {
  union { float f; unsigned u; } a; a.f = f;
  unsigned r = a.u + 0x7fffu + ((a.u >> 16) & 1u);
  return (u16)(r >> 16);
}
// pack two f32 -> u32 of 2 bf16 (lo = first arg), RNE
static __device__ __forceinline__ unsigned cvtpk(float lo, float hi) {
  unsigned r;
  asm("v_cvt_pk_bf16_f32 %0, %1, %2" : "=v"(r) : "v"(lo), "v"(hi));
  return r;
}

// global(16B per lane, per-lane src addr) -> LDS (wave-uniform base + lane*16)
static __device__ __forceinline__ void gload16(const void* g, void* l) {
  __builtin_amdgcn_global_load_lds(
      (__attribute__((address_space(1))) unsigned int*)g,
      (__attribute__((address_space(3))) unsigned int*)l, 16, 0, 0);
}

// ---------------- merged prep: weight casts + 2x LayerNorm ----------------
// blocks 0..12287: f32->bf16 weight cast (Wq pre-scaled by LOG2E/8)
// blocks 12288..20479: LN rows (0..4095 q_x, 4096..8191 kv_x)
__global__ __launch_bounds__(256) void prep_k(
    const float* __restrict__ Wq, const float* __restrict__ Wkv,
    const float* __restrict__ Wo, const float* __restrict__ W1,
    const float* __restrict__ W2,
    u16* __restrict__ wq_b, u16* __restrict__ wkv_b, u16* __restrict__ wo_b,
    u16* __restrict__ w1_b, u16* __restrict__ w2_b,
    const float* __restrict__ xq, const float* __restrict__ xk,
    const float* __restrict__ gq, const float* __restrict__ bq,
    const float* __restrict__ gk, const float* __restrict__ bk,
    u16* __restrict__ oq, u16* __restrict__ ok)
{
  const int blk = blockIdx.x, t = threadIdx.x;
  if (blk < 12288) {
    const int i = blk * 256 + t;   // float4-chunk id
    const float* src; u16* dst; int off; float sc = 1.0f;
    if      (i <  262144) { src = Wq;  dst = wq_b;  off = i; sc = 0.125f * LOG2E; }
    else if (i <  786432) { src = Wkv; dst = wkv_b; off = i -  262144; }
    else if (i < 1048576) { src = Wo;  dst = wo_b;  off = i -  786432; }
    else if (i < 2097152) { src = W1;  dst = w1_b;  off = i - 1048576; }
    else                  { src = W2;  dst = w2_b;  off = i - 2097152; }
    const float4 v = ((const float4*)src)[off];
    ushort4 o;
    o.x = f2bf(v.x * sc); o.y = f2bf(v.y * sc); o.z = f2bf(v.z * sc); o.w = f2bf(v.w * sc);
    ((ushort4*)dst)[off] = o;
    return;
  }
  int row = blk - 12288;
  const float* x; const float* gam; const float* bet; u16* out;
  if (row < 4096) { x = xq; gam = gq; bet = bq; out = oq; }
  else { row -= 4096; x = xk; gam = gk; bet = bk; out = ok; }
  const float4 v = ((const float4*)(x + (size_t)row * 1024))[t];
  float s  = v.x + v.y + v.z + v.w;
  float ss = v.x*v.x + v.y*v.y + v.z*v.z + v.w*v.w;
  #pragma unroll
  for (int m = 1; m < 64; m <<= 1) { s += __shfl_xor(s, m); ss += __shfl_xor(ss, m); }
  __shared__ float red[8];
  const int w = t >> 6;
  if ((t & 63) == 0) { red[w] = s; red[4 + w] = ss; }
  __syncthreads();
  s  = red[0] + red[1] + red[2] + red[3];
  ss = red[4] + red[5] + red[6] + red[7];
  const float mu   = s * (1.0f / 1024.0f);
  const float rstd = rsqrtf(ss * (1.0f / 1024.0f) - mu * mu + 1e-5f);
  const float4 gv = ((const float4*)gam)[t];
  const float4 bv = ((const float4*)bet)[t];
  ushort4 o;
  o.x = f2bf((v.x - mu) * rstd * gv.x + bv.x);
  o.y = f2bf((v.y - mu) * rstd * gv.y + bv.y);
  o.z = f2bf((v.z - mu) * rstd * gv.z + bv.z);
  o.w = f2bf((v.w - mu) * rstd * gv.w + bv.w);
  ((ushort4*)(out + (size_t)row * 1024))[t] = o;
}

// ---------------- GEMM: C[M,N] = A[M,K] @ B[N,K]^T ----------------
// 128x128 tile, 512 threads / 8 waves (4 wr x 2 wc, wave = 32x64 = 2x4 frags),
// BK=64, double-buffered, T2 XOR-swizzled LDS (pre-swizzled global source).
template<int BIAS, int RES, int SILU, int OF32, int OBF>
static __device__ __forceinline__ void gemm_body(
    const u16* __restrict__ A, const u16* __restrict__ B,
    u16* __restrict__ Cb, float* __restrict__ Cf,
    const float* __restrict__ bias, const float* __restrict__ resid,
    int N, int K, int bid, u16* smem)
{
  const int tid = threadIdx.x;
  const int w = tid >> 6, l = tid & 63;
  const int g = l >> 4, q = l & 15;
  const int ntn = N >> 7;
  const int bm = bid / ntn, bn = bid - bm * ntn;
  const int wr = w >> 1, wc = w & 1;
  const int sw = (q & 7) << 4;
  f32x4 acc[2][4] = {};

  const size_t abase = (size_t)(bm * 128) * K;
  const size_t bbase = (size_t)(bn * 128) * K;

  // smem: A[2][128*64], B[2][128*64] u16 (64 KB total)
  auto stage = [&](int buf, int k0) {
    u16* as = smem + buf * 8192;
    u16* bs = smem + 16384 + buf * 8192;
    #pragma unroll
    for (int r = 0; r < 2; ++r) {
      const int c = (r << 9) + tid;            // chunk 0..1023 (16B each)
      const int row = c >> 3, part = c & 7;    // 128 rows x 8 parts
      const int sp = part ^ (row & 7);         // inverse-swizzled source part
      gload16(A + abase + (size_t)row * K + k0 + sp * 8,
              as + (size_t)((r << 9) + (w << 6)) * 8);
      gload16(B + bbase + (size_t)row * K + k0 + sp * 8,
              bs + (size_t)((r << 9) + (w << 6)) * 8);
    }
  };

  const int NT = K >> 6;
  stage(0, 0);
  asm volatile("s_waitcnt vmcnt(0)" ::: "memory");
  __syncthreads();
  int cur = 0;
  for (int t = 0; t < NT; ++t) {
    if (t + 1 < NT) stage(cur ^ 1, (t + 1) << 6);
    const char* as = (const char*)(smem + cur * 8192);
    const char* bs = (const char*)(smem + 16384 + cur * 8192);
    #pragma unroll
    for (int ks = 0; ks < 2; ++ks) {
      s16x8 af[2], bfr[4];
      #pragma unroll
      for (int m = 0; m < 2; ++m)
        af[m] = *(const s16x8*)(as + (size_t)(wr * 32 + m * 16 + q) * 128 +
                                ((ks * 64 + g * 16) ^ sw));
      #pragma unroll
      for (int n = 0; n < 4; ++n)
        bfr[n] = *(const s16x8*)(bs + (size_t)(wc * 64 + n * 16 + q) * 128 +
                                 ((ks * 64 + g * 16) ^ sw));
      #pragma unroll
      for (int m = 0; m < 2; ++m)
        #pragma unroll
        for (int n = 0; n < 4; ++n)
          acc[m][n] = __builtin_amdgcn_mfma_f32_16x16x32_bf16(af[m], bfr[n], acc[m][n], 0, 0, 0);
    }
    asm volatile("s_waitcnt vmcnt(0)" ::: "memory");
    __syncthreads();
    cur ^= 1;
  }

  #pragma unroll
  for (int m = 0; m < 2; ++m) {
    const int row0 = bm * 128 + wr * 32 + m * 16 + g * 4;
    #pragma unroll
    for (int n = 0; n < 4; ++n) {
      const int col = bn * 128 + wc * 64 + n * 16 + q;
      float bv = 0.0f;
      if (BIAS) bv = bias[col];
      #pragma unroll
      for (int r = 0; r < 4; ++r) {
        const size_t idx = (size_t)(row0 + r) * N + col;
        float v = acc[m][n][r] + bv;
        if (RES)  v += resid[idx];
        if (SILU) v = v / (1.0f + __expf(-v));
        if (OF32) Cf[idx] = v;
        if (OBF)  Cb[idx] = f2bf(v);
      }
    }
  }
}

template<int BIAS, int RES, int SILU, int OF32, int OBF>
__global__ __launch_bounds__(512, 4) void gemm_k(
    const u16* __restrict__ A, const u16* __restrict__ B,
    u16* __restrict__ Cb, float* __restrict__ Cf,
    const float* __restrict__ bias, const float* __restrict__ resid,
    int N, int K)
{
  __shared__ u16 smem[32768];
  gemm_body<BIAS, RES, SILU, OF32, OBF>(A, B, Cb, Cf, bias, resid, N, K, blockIdx.x, smem);
}

// q-proj (blocks 0..255) and kv-proj (blocks 256..767) merged
__global__ __launch_bounds__(512, 4) void gemm_qkv_k(
    const u16* __restrict__ lnq, const u16* __restrict__ wq, u16* __restrict__ qp,
    const u16* __restrict__ lnk, const u16* __restrict__ wkv, u16* __restrict__ kvp)
{
  __shared__ u16 smem[32768];
  if (blockIdx.x < 256)
    gemm_body<0,0,0,0,1>(lnq, wq, qp, nullptr, nullptr, nullptr, 1024, 1024, blockIdx.x, smem);
  else
    gemm_body<0,0,0,0,1>(lnk, wkv, kvp, nullptr, nullptr, nullptr, 2048, 1024, blockIdx.x - 256, smem);
}

// ---------------- Flash attention (swapped QK^T, lane-local P, dbuf K/V) ----------------
// grid = bh*32 + qtile. 4 waves x 16 q-rows (Q-tile 64). KV-tile 64, dbuf.
// S^T = mfma(K,Q): lane (g,q) holds S^T[k=16nf+4g+r][q] -> softmax is
// lane-local + 2 shfl_xor. PV A-fragment is ALSO lane-local: P[q][32s+4g+r]
// = sacc[2s][r], P[q][32s+16+4g+r] = sacc[2s+1][r] (same k-permutation as
// the V tr-read) -> no P LDS round trip at all. Q arrives pre-scaled by
// LOG2E/8 so softmax runs directly in the exp2 domain.
__global__ __launch_bounds__(256, 4) void attn_k(
    const u16* __restrict__ Q, const u16* __restrict__ KV, u16* __restrict__ O)
{
  __shared__ u16 Ks[2][64 * 64];
  __shared__ u16 Vs[2][64 * 64];
  const int tid = threadIdx.x;
  const int w = tid >> 6, l = tid & 63;
  const int g = l >> 4, q = l & 15;
  const int bh = blockIdx.x >> 5, qt = blockIdx.x & 31;
  const int b = bh >> 4, h = bh & 15;

  // Q fragments (this wave's 16 rows x 64)
  const size_t qrow = (size_t)(b * 2048 + qt * 64 + w * 16 + q);
  s16x8 qf[2];
  qf[0] = *(const s16x8*)&Q[qrow * 1024 + h * 64 + g * 8];
  qf[1] = *(const s16x8*)&Q[qrow * 1024 + h * 64 + 32 + g * 8];

  f32x4 oacc[4] = {};
  float mrow = -1e30f, lrow = 0.0f;

  const u16* kvb = KV + (size_t)b * 2048 * 2048;
  const unsigned vs_base =
      (unsigned)(unsigned long long)(__attribute__((address_space(3))) u16*)Vs;

  auto stage = [&](int buf, int kv0) {
    #pragma unroll
    for (int r = 0; r < 2; ++r) {
      const int c = (r << 8) + tid;                   // chunk 0..511
      // K: row-major [64][64], 16B slots XOR-pre-swizzled at the global source
      const int krow = c >> 3, slot = c & 7;
      gload16(kvb + (size_t)(kv0 + krow) * 2048 + h * 64 + ((slot ^ (krow & 7)) << 3),
              &Ks[buf][(size_t)((r << 8) + (w << 6)) * 8]);
      // V: subtiled [(d>>4)*16 + (kv>>2)][(kv&3)*16 + (d&15)] for tr_b16 reads
      const int vkv = ((c >> 3) & 15) * 4 + ((c >> 1) & 3);
      const int vd0 = ((c >> 7) & 3) * 16 + (c & 1) * 8;
      gload16(kvb + (size_t)(kv0 + vkv) * 2048 + 1024 + h * 64 + vd0,
              &Vs[buf][(size_t)((r << 8) + (w << 6)) * 8]);
    }
  };

  stage(0, 0);
  asm volatile("s_waitcnt vmcnt(0)" ::: "memory");
  __syncthreads();
  int cur = 0;

  for (int kt = 0; kt < 32; ++kt) {
    if (kt + 1 < 32) stage(cur ^ 1, (kt + 1) * 64);

    // S^T = K @ Q^T: sacc[nf] reg r = S^T[k = nf*16 + g*4 + r][qrow = q]
    const char* ksb = (const char*)Ks[cur];
    f32x4 sacc[4] = {};
    __builtin_amdgcn_s_setprio(1);
    #pragma unroll
    for (int s = 0; s < 2; ++s)
      #pragma unroll
      for (int nf = 0; nf < 4; ++nf) {
        const int krw = nf * 16 + q;
        const s16x8 kf = *(const s16x8*)(ksb + krw * 128 +
                              ((s * 64 + g * 16) ^ ((krw & 7) << 4)));
        sacc[nf] = __builtin_amdgcn_mfma_f32_16x16x32_bf16(kf, qf[s], sacc[nf], 0, 0, 0);
      }
    __builtin_amdgcn_s_setprio(0);

    // per-lane softmax (log2 domain) over 16 k-values, then 2 shfl_xor across g
    float mx = sacc[0][0];
    #pragma unroll
    for (int nf = 0; nf < 4; ++nf)
      #pragma unroll
      for (int r = 0; r < 4; ++r) mx = fmaxf(mx, sacc[nf][r]);
    mx = fmaxf(mx, __shfl_xor(mx, 16));
    mx = fmaxf(mx, __shfl_xor(mx, 32));
    if (__any(mx > mrow + 8.0f)) {          // defer-max (T13)
      const float mnew = fmaxf(mrow, mx);
      const float al = __builtin_amdgcn_exp2f(mrow - mnew);
      lrow *= al;
      float ar[4];
      #pragma unroll
      for (int r = 0; r < 4; ++r) ar[r] = __shfl(al, g * 4 + r);
      #pragma unroll
      for (int nf = 0; nf < 4; ++nf)
        #pragma unroll
        for (int r = 0; r < 4; ++r) oacc[nf][r] *= ar[r];
      mrow = mnew;
    }
    float rs = 0.0f;
    #pragma unroll
    for (int nf = 0; nf < 4; ++nf)
      #pragma unroll
      for (int r = 0; r < 4; ++r) {
        const float e = __builtin_amdgcn_exp2f(sacc[nf][r] - mrow);
        sacc[nf][r] = e; rs += e;
      }
    rs += __shfl_xor(rs, 16);
    rs += __shfl_xor(rs, 32);
    lrow += rs;

    // O += P @ V ; PA fragments are lane-local repacks of sacc
    const unsigned vsb = vs_base + (unsigned)(cur << 13);
    __builtin_amdgcn_s_setprio(1);
    #pragma unroll
    for (int s = 0; s < 2; ++s) {
      union { u32x4 u; s16x8 s8; } au;
      au.u[0] = cvtpk(sacc[2*s  ][0], sacc[2*s  ][1]);
      au.u[1] = cvtpk(sacc[2*s  ][2], sacc[2*s  ][3]);
      au.u[2] = cvtpk(sacc[2*s+1][0], sacc[2*s+1][1]);
      au.u[3] = cvtpk(sacc[2*s+1][2], sacc[2*s+1][3]);
      #pragma unroll
      for (int nf = 0; nf < 4; ++nf) {
        // tr-read: lane gets 4 bf16 at addr + {0,32,64,96}B = kv, kv+1, kv+2, kv+3
        const unsigned a1 = vsb + (unsigned)((nf * 16 + 8 * s + g) * 128 + 2 * q);
        u32x2 t1, t2;
        asm volatile("ds_read_b64_tr_b16 %0, %2\n\t"
                     "ds_read_b64_tr_b16 %1, %2 offset:512\n\t"
                     "s_waitcnt lgkmcnt(0)"
                     : "=&v"(t1), "=&v"(t2) : "v"(a1) : "memory");
        __builtin_amdgcn_sched_barrier(0);
        union { u32x4 u; s16x8 s8; } bu;
        bu.u[0] = t1[0]; bu.u[1] = t1[1]; bu.u[2] = t2[0]; bu.u[3] = t2[1];
        oacc[nf] = __builtin_amdgcn_mfma_f32_16x16x32_bf16(au.s8, bu.s8, oacc[nf], 0, 0, 0);
      }
    }
    __builtin_amdgcn_s_setprio(0);

    asm volatile("s_waitcnt vmcnt(0)" ::: "memory");
    __syncthreads();
    cur ^= 1;
  }

  float lr[4];
  #pragma unroll
  for (int r = 0; r < 4; ++r) lr[r] = __shfl(lrow, g * 4 + r);
  const size_t ob = (size_t)(b * 2048 + qt * 64 + w * 16) * 1024 + h * 64;
  #pragma unroll
  for (int r = 0; r < 4; ++r) {
    const float inv = 1.0f / lr[r];
    #pragma unroll
    for (int nf = 0; nf < 4; ++nf)
      O[ob + (size_t)(g * 4 + r) * 1024 + nf * 16 + q] = f2bf(oacc[nf][r] * inv);
  }
}

// ---------------- launch ----------------
extern "C" void kernel_launch(void* const* d_in, const int* in_sizes, int n_in,
                              void* d_out, int out_size, void* d_ws, size_t ws_size,
                              hipStream_t stream)
{
  const float* q_x  = (const float*)d_in[0];
  const float* kv_x = (const float*)d_in[1];
  const float* Wq   = (const float*)d_in[2];
  const float* Wkv  = (const float*)d_in[3];
  const float* Wo   = (const float*)d_in[4];
  const float* bo   = (const float*)d_in[5];
  const float* lnqg = (const float*)d_in[6];
  const float* lnqb = (const float*)d_in[7];
  const float* lnkg = (const float*)d_in[8];
  const float* lnkb = (const float*)d_in[9];
  const float* W1   = (const float*)d_in[10];
  const float* b1   = (const float*)d_in[11];
  const float* W2   = (const float*)d_in[12];
  const float* b2   = (const float*)d_in[13];
  float* out = (float*)d_out;

  char* ws = (char*)d_ws;
  const size_t MB = 1024 * 1024;
  u16*   wq_b  = (u16*)  (ws +  0 * MB);   // 2 MB
  u16*   wkv_b = (u16*)  (ws +  2 * MB);   // 4 MB
  u16*   wo_b  = (u16*)  (ws +  6 * MB);   // 2 MB
  u16*   w1_b  = (u16*)  (ws +  8 * MB);   // 8 MB
  u16*   w2_b  = (u16*)  (ws + 16 * MB);   // 8 MB
  u16*   lnq   = (u16*)  (ws + 24 * MB);   // 8 MB
  u16*   lnk   = (u16*)  (ws + 32 * MB);   // 8 MB
  u16*   qp    = (u16*)  (ws + 40 * MB);   // 8 MB
  u16*   kvp   = (u16*)  (ws + 48 * MB);   // 16 MB
  u16*   ao    = (u16*)  (ws + 64 * MB);   // 8 MB
  float* xf    = (float*)(ws + 72 * MB);   // 16 MB
  u16*   xb    = (u16*)  (ws + 88 * MB);   // 8 MB
  u16*   hb    = (u16*)  (ws + 96 * MB);   // 32 MB -> 128 MB total

  prep_k<<<dim3(20480), dim3(256), 0, stream>>>(
      Wq, Wkv, Wo, W1, W2, wq_b, wkv_b, wo_b, w1_b, w2_b,
      q_x, kv_x, lnqg, lnqb, lnkg, lnkb, lnq, lnk);

  // q = LN(q_x) @ (Wq*LOG2E/8)^T ; kv = LN(kv_x) @ Wkv^T (merged)
  gemm_qkv_k<<<dim3(768), dim3(512), 0, stream>>>(lnq, wq_b, qp, lnk, wkv_b, kvp);
  // flash attention
  attn_k<<<dim3(1024), dim3(256), 0, stream>>>(qp, kvp, ao);
  // x = q_x + ao @ Wo^T + bo   (store f32 + bf16)
  gemm_k<1,1,0,1,1><<<dim3(256),  dim3(512), 0, stream>>>(
      ao, wo_b, xb, xf, bo, q_x, 1024, 1024);
  // h = silu(x @ W1^T + b1)
  gemm_k<1,0,1,0,1><<<dim3(1024), dim3(512), 0, stream>>>(
      xb, w1_b, hb, nullptr, b1, nullptr, 4096, 1024);
  // out = x + h @ W2^T + b2    (f32)
  gemm_k<1,1,0,1,0><<<dim3(256),  dim3(512), 0, stream>>>(
      hb, w2_b, nullptr, out, b2, xf, 1024, 4096);
}